// Round 23
// baseline (103.343 us; speedup 1.0000x reference)
//
#include <hip/hip_runtime.h>

typedef unsigned short u16;
typedef unsigned int u32;
typedef __attribute__((ext_vector_type(8))) short short8v;   // 8 bf16 (4 VGPRs)
typedef __attribute__((ext_vector_type(4))) float f32x4;
typedef __attribute__((ext_vector_type(16))) float f32x16;
typedef __attribute__((ext_vector_type(2))) int i32x2;

#define B 2
#define NF 5
#define C 256
#define HW 4096
#define CV 128
#define NK 16384   // 4 frames * 4096
#define NQ 4096

__device__ __forceinline__ u16 f2bf(float f) {
    u32 u = __float_as_uint(f);
    u32 r = (u + 0x7FFFu + ((u >> 16) & 1u)) >> 16;   // RNE
    return (u16)r;
}

__device__ __forceinline__ u32 cvtpk(float lo, float hi) {
    u32 r;
    asm("v_cvt_pk_bf16_f32 %0, %1, %2" : "=v"(r) : "v"(lo), "v"(hi));
    return r;
}

// raw v_exp_f32 (2^x). Inputs bounded |x|<=~1.5 here, so OCML's denormal
// fixup path (~4-5 extra VALU per call) is dead weight.
__device__ __forceinline__ float exp2_raw(float x) {
    float r;
    asm("v_exp_f32 %0, %1" : "=v"(r) : "v"(x));
    return r;
}

// vdst'[0:31]=src0[32:63]; src0'[32:63]=vdst[0:31]; other halves keep.
__device__ __forceinline__ i32x2 plswap(u32 vdst, u32 src0) {
    return __builtin_amdgcn_permlane32_swap((int)vdst, (int)src0, false, false);
}

// ---------------- prep: bf16 weight tables + BN folding ----------------
__global__ __launch_bounds__(256) void prep_k(
    const float* __restrict__ qk_w, const float* __restrict__ qv_w,
    const float* __restrict__ mk_w, const float* __restrict__ mv_w,
    const float* __restrict__ sm_w,
    const float* __restrict__ bns, const float* __restrict__ bnb,
    const float* __restrict__ bnm, const float* __restrict__ bnv,
    u16* __restrict__ wsf, float* __restrict__ bias2, u16* __restrict__ wb) {
    int bx = blockIdx.x, t = threadIdx.x;
    if (bx < 256) {
        int idx = bx * 256 + t;          // o*256 + c
        int o = idx >> 8;
        float inv = bns[o] / sqrtf(bnv[o] + 1e-5f);
        wsf[idx] = f2bf(sm_w[idx] * inv);
    } else if (bx < 576) {
        int j = (bx - 256) * 256 + t;    // < 81920
        int v = j / 40960, rr = j % 40960;
        int row = rr >> 8, c = rr & 255;
        float s;
        if (v == 0) s = (row < 32) ? mk_w[row * 256 + c] : mv_w[(row - 32) * 256 + c];
        else        s = (row < 32) ? qk_w[row * 256 + c] : qv_w[(row - 32) * 256 + c];
        wb[j] = f2bf(s);
    } else {
        int o = t;
        float inv = bns[o] / sqrtf(bnv[o] + 1e-5f);
        bias2[o] = bnb[o] - bnm[o] * inv;
    }
}

// ---------------- fused K+V projection via MFMA (+xm frame write-through) ----------------
// R15/R17-measured form (proj at its structural floor: VALU-pack (R16) and
// TLP-split (R19) both A/B'd neutral-to-negative; it's HBM+launch bound).
// qkn is pre-scaled by log2(e): attn computes P = exp2(S_scaled) = e^S.
__global__ __launch_bounds__(256) void proj_mfma(
    const float* __restrict__ x, const u16* __restrict__ wb,
    u16* __restrict__ qkn, u16* __restrict__ mkn,
    u16* __restrict__ mvt, u16* __restrict__ U, float* __restrict__ out) {
    int bx = blockIdx.x;        // 2*5*64 = 640
    int bi = bx / 320;
    int rem = bx % 320;
    int f = rem >> 6, pt = rem & 63;
    int t = threadIdx.x, w = t >> 6, lane = t & 63;
    int l15 = lane & 15, cg = lane >> 4;
    int p = pt * 64 + w * 16 + l15;
    const float* xp = x + (((size_t)bi * NF + f) * C) * HW + p;
    const u16* wrow = wb + (size_t)((f == 4) ? 160 : 0) * 256;
    float* op = out + (((size_t)bi * NF + f) * C) * HW + p;   // frames 0..3 pass-through

    f32x4 acc[10];
#pragma unroll
    for (int m = 0; m < 10; m++) acc[m] = (f32x4){0.f, 0.f, 0.f, 0.f};

    for (int k = 0; k < 8; k++) {
        float xv[8];
#pragma unroll
        for (int j = 0; j < 8; j++) xv[j] = xp[(size_t)(k * 32 + cg * 8 + j) * HW];
        if (f < 4) {   // fused xm copy (block-uniform branch)
#pragma unroll
            for (int j = 0; j < 8; j++) op[(size_t)(k * 32 + cg * 8 + j) * HW] = xv[j];
        }
        short8v bfrag;
#pragma unroll
        for (int j = 0; j < 8; j++) bfrag[j] = (short)f2bf(xv[j]);
#pragma unroll
        for (int m = 0; m < 10; m++) {
            short8v afrag = *(const short8v*)(wrow + (size_t)(m * 16 + l15) * 256 + k * 32 + cg * 8);
            acc[m] = __builtin_amdgcn_mfma_f32_16x16x32_bf16(afrag, bfrag, acc[m], 0, 0, 0);
        }
    }

    float ssq = 0.f;
#pragma unroll
    for (int m = 0; m < 2; m++)
#pragma unroll
        for (int r = 0; r < 4; r++) ssq += acc[m][r] * acc[m][r];
    ssq += __shfl_xor(ssq, 16, 64);
    ssq += __shfl_xor(ssq, 32, 64);
    float rn = 1.0f / fmaxf(sqrtf(ssq), 1e-12f);

    if (f == 4) {
        float rq = rn * 1.44269504f;   // fold log2(e) into Q
        u16* kd = qkn + ((size_t)bi * NQ + p) * 32;
#pragma unroll
        for (int m = 0; m < 2; m++)
#pragma unroll
            for (int r = 0; r < 4; r++) kd[m * 16 + cg * 4 + r] = f2bf(acc[m][r] * rq);
        u16* ud = U + ((size_t)bi * HW + p) * 256;
#pragma unroll
        for (int m = 2; m < 10; m++) {
            int vo = m * 16 - 32 + cg * 4;
            union { u16 h[4]; uint2 v; } pk;
#pragma unroll
            for (int r = 0; r < 4; r++) pk.h[r] = f2bf(acc[m][r]);
            *(uint2*)(ud + vo) = pk.v;
        }
    } else {
        u16* kd = mkn + ((size_t)bi * NK + f * HW + p) * 32;
#pragma unroll
        for (int m = 0; m < 2; m++)
#pragma unroll
            for (int r = 0; r < 4; r++) kd[m * 16 + cg * 4 + r] = f2bf(acc[m][r] * rn);
#pragma unroll
        for (int m = 2; m < 10; m++)
#pragma unroll
            for (int r = 0; r < 4; r++) {
                int vo = m * 16 - 32 + cg * 4 + r;
                mvt[((size_t)bi * CV + vo) * NK + f * HW + p] = f2bf(acc[m][r]);
            }
    }
}

// ---------------- flash attention v16: V-only LDS, K in registers ----------------
// R22 diagnostic: throughput independent of 2-vs-3 blocks/CU -> pipe-bound, and
// LDS is the pole (25 b128 instrs/iter/wave ~ 300cy > MFMA 160 > VALU 160).
// K's share is 5 of those (1 staged write + 4 frag reads); K fragments are
// per-lane addressable from global (row it*64+t*32+l31, col hi*8), and the
// 128KB K-chunk is shared by 64 blocks -> L2-hot (R9 measured FETCH 7.2MB for
// this exact pattern). So: kl[] deleted, K prefetched into 4 regs pre-barrier
// alongside V. LDS 47104 -> 36864. kc=8, padded V rows, raw v_exp, setprio,
// pre-barrier prefetch -- all unchanged from the 102.3-us R22 config.
__global__ __launch_bounds__(256, 2) void attn_k(
    const u16* __restrict__ qkn, const u16* __restrict__ mkn,
    const u16* __restrict__ mvt, u16* __restrict__ opart,
    float* __restrict__ lpart, int kc) {
    __shared__ alignas(16) u16 vl[2][128 * 72];   // [128 v][64 k + 8 pad] (144B rows)

    int bx = blockIdx.x;
    int bi = bx / (32 * kc);
    int rem = bx % (32 * kc);
    int qt = rem / kc, kci = rem % kc;
    int chunk = NK / kc, iters = chunk / 64;
    int tid = threadIdx.x, w = tid >> 6, lane = tid & 63;
    int l31 = lane & 31, hi = lane >> 5;

    int qrow = qt * 128 + w * 32 + l31;
    const u16* qp = qkn + ((size_t)bi * NQ + qrow) * 32;
    short8v qf0 = *(const short8v*)(qp + hi * 8);
    short8v qf1 = *(const short8v*)(qp + 16 + hi * 8);

    f32x16 O[4];
#pragma unroll
    for (int n = 0; n < 4; n++)
#pragma unroll
        for (int i = 0; i < 16; i++) O[n][i] = 0.f;
    float ls[4] = {0.f, 0.f, 0.f, 0.f};

    const u16* mknb = mkn + (size_t)bi * NK * 32;
    const u16* mvtb = mvt + (size_t)bi * CV * NK;
    // per-lane K base: row (kci*chunk + l31), byte col hi*16 (c = hi*8..hi*8+7)
    const u16* kg = mknb + ((size_t)kci * chunk + l31) * 32 + hi * 8;

    int vrow[4], vcol[4], vlsoff[4];
#pragma unroll
    for (int r = 0; r < 4; r++) {
        int cidx = tid + 256 * r;
        vrow[r] = cidx >> 3; vcol[r] = cidx & 7;
        vlsoff[r] = vrow[r] * 72 + vcol[r] * 8;   // padded, no swizzle
    }
    const u16* vptr[4];
#pragma unroll
    for (int r = 0; r < 4; r++)
        vptr[r] = mvtb + (size_t)vrow[r] * NK + kci * chunk + vcol[r] * 8;

    // prologue: tile 0 loads (V staging regs + K fragment regs)
    short8v vreg[4];
#pragma unroll
    for (int r = 0; r < 4; r++) vreg[r] = *(const short8v*)vptr[r];
    short8v kp0 = *(const short8v*)kg;
    short8v kp1 = *(const short8v*)(kg + 16);
    short8v kp2 = *(const short8v*)(kg + 32 * 32);
    short8v kp3 = *(const short8v*)(kg + 32 * 32 + 16);

    int c = 0;
    for (int it = 0; it < iters; ++it) {
        // stage V tile into buf c
#pragma unroll
        for (int r = 0; r < 4; r++) *(short8v*)(&vl[c][0] + vlsoff[r]) = vreg[r];
        // capture this iter's K frags, then prefetch next tile (pre-barrier
        // issue: proven +7us vs post-barrier in R13->R14 A/B)
        short8v ka[2][2] = {{kp0, kp1}, {kp2, kp3}};
        if (it + 1 < iters) {
#pragma unroll
            for (int r = 0; r < 4; r++) {
                vptr[r] += 64;
                vreg[r] = *(const short8v*)vptr[r];
            }
            const u16* kgn = kg + (size_t)(it + 1) * 64 * 32;
            kp0 = *(const short8v*)kgn;
            kp1 = *(const short8v*)(kgn + 16);
            kp2 = *(const short8v*)(kgn + 32 * 32);
            kp3 = *(const short8v*)(kgn + 32 * 32 + 16);
        }
        __syncthreads();
        const u16* vlr = &vl[c][0];
#pragma unroll
        for (int t = 0; t < 2; t++) {
            f32x16 st;
#pragma unroll
            for (int i = 0; i < 16; i++) st[i] = 0.f;
            __builtin_amdgcn_s_setprio(1);
            st = __builtin_amdgcn_mfma_f32_32x32x16_bf16(ka[t][0], qf0, st, 0, 0, 0);
            st = __builtin_amdgcn_mfma_f32_32x32x16_bf16(ka[t][1], qf1, st, 0, 0, 0);
            __builtin_amdgcn_s_setprio(0);
            float p[16];
#pragma unroll
            for (int i = 0; i < 16; i++) p[i] = exp2_raw(st[i]);
#pragma unroll
            for (int g = 0; g < 4; g++)
                ls[g] += ((p[4 * g] + p[4 * g + 1]) + (p[4 * g + 2] + p[4 * g + 3]));
            u32 c0[4], c1[4];
#pragma unroll
            for (int g = 0; g < 4; g++) {
                c0[g] = cvtpk(p[4 * g], p[4 * g + 1]);       // keys 8g+4hi+{0,1}
                c1[g] = cvtpk(p[4 * g + 2], p[4 * g + 3]);   // keys 8g+4hi+{2,3}
            }
#pragma unroll
            for (int half = 0; half < 2; half++) {
                i32x2 s0 = plswap(c0[2 * half + 1], c0[2 * half]);
                i32x2 s1 = plswap(c1[2 * half + 1], c1[2 * half]);
                union { u32 wd[4]; short8v v; } bu;
                bu.wd[0] = (u32)s0[1];
                bu.wd[1] = (u32)s1[1];
                bu.wd[2] = (u32)s0[0];
                bu.wd[3] = (u32)s1[0];
                int kk = 2 * t + half;
                __builtin_amdgcn_s_setprio(1);
#pragma unroll
                for (int n = 0; n < 4; n++) {
                    int vr = n * 32 + l31;
                    short8v va = *(const short8v*)(vlr + vr * 72 + (kk * 2 + hi) * 8);
                    O[n] = __builtin_amdgcn_mfma_f32_32x32x16_bf16(va, bu.v, O[n], 0, 0, 0);
                }
                __builtin_amdgcn_s_setprio(0);
            }
        }
        c ^= 1;
    }

    float lsum = (ls[0] + ls[1]) + (ls[2] + ls[3]);
    lsum += __shfl_xor(lsum, 32, 64);
    uint2* op2 = (uint2*)opart;
    size_t pbase4 = (size_t)(bi * kc + kci) * 32;
#pragma unroll
    for (int n = 0; n < 4; n++)
#pragma unroll
        for (int g = 0; g < 4; g++) {
            uint2 val;
            val.x = cvtpk(O[n][4 * g + 0], O[n][4 * g + 1]);
            val.y = cvtpk(O[n][4 * g + 2], O[n][4 * g + 3]);
            int v4 = n * 8 + 2 * g + hi;   // v quad = (n*32 + 8g + 4hi)/4
            op2[(pbase4 + v4) * NQ + qrow] = val;
        }
    if (hi == 0) lpart[(size_t)(bi * kc + kci) * NQ + qrow] = lsum;
}

// ---------------- fused combine + output GEMM (+folded BN+ReLU) ----------------
// R17-measured form (32 px/block, grid 256). phase 1: sum kc bf16 partials,
// scale by 1/sum(l), stage agg in padded LDS; phase 2: 256x32 GEMM from
// U + agg-LDS, bias+relu. kc=8 halves phase-1 traffic (R22: -5.4 us total).
__global__ __launch_bounds__(256) void final_fused(
    const u16* __restrict__ opart, const float* __restrict__ lpart,
    const u16* __restrict__ U, const u16* __restrict__ wsf,
    const float* __restrict__ bias2, float* __restrict__ out, int kc) {
    __shared__ alignas(16) u16 aggL[32][136];   // [px][128 ch + 8 pad]
    __shared__ float lsumL[32];

    int bx = blockIdx.x;          // 2*128 = 256
    int bi = bx >> 7;
    int q0 = (bx & 127) * 32;
    int t = threadIdx.x;
    int px = t & 31, qs = t >> 5;   // qs 0..7

    if (qs == 0) {
        float s = 0.f;
        for (int k = 0; k < kc; k++) s += lpart[(size_t)(bi * kc + k) * NQ + q0 + px];
        lsumL[px] = 1.0f / s;
    }
    const uint2* op2 = (const uint2*)opart;
    float s[4][4];
#pragma unroll
    for (int j = 0; j < 4; j++)
#pragma unroll
        for (int e = 0; e < 4; e++) s[j][e] = 0.f;
    for (int k = 0; k < kc; k++) {
        size_t kb = (size_t)(bi * kc + k) * 32;
#pragma unroll
        for (int j = 0; j < 4; j++) {
            uint2 d = op2[(kb + qs * 4 + j) * NQ + q0 + px];
            s[j][0] += __uint_as_float(d.x << 16);
            s[j][1] += __uint_as_float(d.x & 0xFFFF0000u);
            s[j][2] += __uint_as_float(d.y << 16);
            s[j][3] += __uint_as_float(d.y & 0xFFFF0000u);
        }
    }
    __syncthreads();   // lsumL ready
    float r = lsumL[px];
#pragma unroll
    for (int j = 0; j < 4; j++) {
        uint2 v;
        v.x = cvtpk(s[j][0] * r, s[j][1] * r);
        v.y = cvtpk(s[j][2] * r, s[j][3] * r);
        *(uint2*)(&aggL[px][(qs * 4 + j) * 4]) = v;
    }
    __syncthreads();   // aggL ready

    int w = t >> 6, lane = t & 63;
    int l15 = lane & 15, cg = lane >> 4;
    f32x4 acc[4][2];
#pragma unroll
    for (int m = 0; m < 4; m++)
#pragma unroll
        for (int n = 0; n < 2; n++) acc[m][n] = (f32x4){0.f, 0.f, 0.f, 0.f};
    const u16* ub = U + ((size_t)bi * HW + q0) * 256;
    for (int k8 = 0; k8 < 8; k8++) {
        short8v bfrag[2];
#pragma unroll
        for (int n = 0; n < 2; n++) {
            int pxr = n * 16 + l15;
            if (k8 < 4) bfrag[n] = *(const short8v*)(ub + (size_t)pxr * 256 + k8 * 32 + cg * 8);
            else        bfrag[n] = *(const short8v*)(&aggL[pxr][(k8 - 4) * 32 + cg * 8]);
        }
#pragma unroll
        for (int m = 0; m < 4; m++) {
            short8v afrag = *(const short8v*)(wsf + (size_t)(w * 64 + m * 16 + l15) * 256 + k8 * 32 + cg * 8);
#pragma unroll
            for (int n = 0; n < 2; n++)
                acc[m][n] = __builtin_amdgcn_mfma_f32_16x16x32_bf16(afrag, bfrag[n], acc[m][n], 0, 0, 0);
        }
    }
    float* obase = out + (((size_t)bi * NF + 4) * C) * HW;
#pragma unroll
    for (int m = 0; m < 4; m++)
#pragma unroll
        for (int n = 0; n < 2; n++)
#pragma unroll
            for (int rr = 0; rr < 4; rr++) {
                int o = w * 64 + m * 16 + cg * 4 + rr;
                int px2 = n * 16 + l15;
                obase[(size_t)o * HW + q0 + px2] = fmaxf(acc[m][n][rr] + bias2[o], 0.f);
            }
}

extern "C" void kernel_launch(void* const* d_in, const int* in_sizes, int n_in,
                              void* d_out, int out_size, void* d_ws, size_t ws_size,
                              hipStream_t stream) {
    const float* x    = (const float*)d_in[0];
    const float* qk_w = (const float*)d_in[2];
    const float* qv_w = (const float*)d_in[3];
    const float* mk_w = (const float*)d_in[4];
    const float* mv_w = (const float*)d_in[5];
    const float* sm_w = (const float*)d_in[6];
    const float* bns  = (const float*)d_in[7];
    const float* bnb  = (const float*)d_in[8];
    const float* bnm  = (const float*)d_in[9];
    const float* bnv  = (const float*)d_in[10];
    float* out = (float*)d_out;
    char* ws = (char*)d_ws;

    size_t off = 0;
    auto alloc = [&](size_t bytes) { size_t o = off; off += (bytes + 255) & ~(size_t)255; return o; };
    size_t WSF = alloc(256 * 256 * 2);
    size_t BIA = alloc(256 * 4);
    size_t WB  = alloc(2 * 160 * 256 * 2);
    size_t QKN = alloc((size_t)B * NQ * 32 * 2);
    size_t MKN = alloc((size_t)B * NK * 32 * 2);
    size_t MVT = alloc((size_t)B * CV * NK * 2);
    size_t UBU = alloc((size_t)B * HW * 256 * 2);
    int kc = 8;   // R22-measured best: halves opart/lpart traffic
    size_t LP = alloc((size_t)B * kc * NQ * 4);
    size_t OP = alloc((size_t)B * kc * (size_t)CV * NQ * 2);

    prep_k<<<577, 256, 0, stream>>>(qk_w, qv_w, mk_w, mv_w, sm_w, bns, bnb, bnm, bnv,
        (u16*)(ws + WSF), (float*)(ws + BIA), (u16*)(ws + WB));
    proj_mfma<<<640, 256, 0, stream>>>(x, (u16*)(ws + WB),
        (u16*)(ws + QKN), (u16*)(ws + MKN), (u16*)(ws + MVT), (u16*)(ws + UBU), out);
    attn_k<<<B * 32 * kc, 256, 0, stream>>>((u16*)(ws + QKN), (u16*)(ws + MKN),
        (u16*)(ws + MVT), (u16*)(ws + OP), (float*)(ws + LP), kc);
    final_fused<<<256, 256, 0, stream>>>((u16*)(ws + OP), (float*)(ws + LP),
        (u16*)(ws + UBU), (u16*)(ws + WSF), (float*)(ws + BIA), out, kc);
}

// Round 24
// 101.802 us; speedup vs baseline: 1.0151x; 1.0151x over previous
//
#include <hip/hip_runtime.h>

typedef unsigned short u16;
typedef unsigned int u32;
typedef __attribute__((ext_vector_type(8))) short short8v;   // 8 bf16 (4 VGPRs)
typedef __attribute__((ext_vector_type(4))) float f32x4;
typedef __attribute__((ext_vector_type(16))) float f32x16;
typedef __attribute__((ext_vector_type(2))) int i32x2;

#define B 2
#define NF 5
#define C 256
#define HW 4096
#define CV 128
#define NK 16384   // 4 frames * 4096
#define NQ 4096

__device__ __forceinline__ u16 f2bf(float f) {
    u32 u = __float_as_uint(f);
    u32 r = (u + 0x7FFFu + ((u >> 16) & 1u)) >> 16;   // RNE
    return (u16)r;
}

__device__ __forceinline__ u32 cvtpk(float lo, float hi) {
    u32 r;
    asm("v_cvt_pk_bf16_f32 %0, %1, %2" : "=v"(r) : "v"(lo), "v"(hi));
    return r;
}

// raw v_exp_f32 (2^x). Inputs bounded |x|<=~1.5 here, so OCML's denormal
// fixup path (~4-5 extra VALU per call) is dead weight.
__device__ __forceinline__ float exp2_raw(float x) {
    float r;
    asm("v_exp_f32 %0, %1" : "=v"(r) : "v"(x));
    return r;
}

// vdst'[0:31]=src0[32:63]; src0'[32:63]=vdst[0:31]; other halves keep.
__device__ __forceinline__ i32x2 plswap(u32 vdst, u32 src0) {
    return __builtin_amdgcn_permlane32_swap((int)vdst, (int)src0, false, false);
}

// ---------------- prep: bf16 weight tables + BN folding ----------------
__global__ __launch_bounds__(256) void prep_k(
    const float* __restrict__ qk_w, const float* __restrict__ qv_w,
    const float* __restrict__ mk_w, const float* __restrict__ mv_w,
    const float* __restrict__ sm_w,
    const float* __restrict__ bns, const float* __restrict__ bnb,
    const float* __restrict__ bnm, const float* __restrict__ bnv,
    u16* __restrict__ wsf, float* __restrict__ bias2, u16* __restrict__ wb) {
    int bx = blockIdx.x, t = threadIdx.x;
    if (bx < 256) {
        int idx = bx * 256 + t;          // o*256 + c
        int o = idx >> 8;
        float inv = bns[o] / sqrtf(bnv[o] + 1e-5f);
        wsf[idx] = f2bf(sm_w[idx] * inv);
    } else if (bx < 576) {
        int j = (bx - 256) * 256 + t;    // < 81920
        int v = j / 40960, rr = j % 40960;
        int row = rr >> 8, c = rr & 255;
        float s;
        if (v == 0) s = (row < 32) ? mk_w[row * 256 + c] : mv_w[(row - 32) * 256 + c];
        else        s = (row < 32) ? qk_w[row * 256 + c] : qv_w[(row - 32) * 256 + c];
        wb[j] = f2bf(s);
    } else {
        int o = t;
        float inv = bns[o] / sqrtf(bnv[o] + 1e-5f);
        bias2[o] = bnb[o] - bnm[o] * inv;
    }
}

// ---------------- fused K+V projection via MFMA (+xm frame write-through) ----------------
// R15/R17-measured form (proj at its structural floor: VALU-pack (R16) and
// TLP-split (R19) both A/B'd neutral-to-negative; it's HBM+launch bound).
// qkn is pre-scaled by log2(e): attn computes P = exp2(S_scaled) = e^S.
__global__ __launch_bounds__(256) void proj_mfma(
    const float* __restrict__ x, const u16* __restrict__ wb,
    u16* __restrict__ qkn, u16* __restrict__ mkn,
    u16* __restrict__ mvt, u16* __restrict__ U, float* __restrict__ out) {
    int bx = blockIdx.x;        // 2*5*64 = 640
    int bi = bx / 320;
    int rem = bx % 320;
    int f = rem >> 6, pt = rem & 63;
    int t = threadIdx.x, w = t >> 6, lane = t & 63;
    int l15 = lane & 15, cg = lane >> 4;
    int p = pt * 64 + w * 16 + l15;
    const float* xp = x + (((size_t)bi * NF + f) * C) * HW + p;
    const u16* wrow = wb + (size_t)((f == 4) ? 160 : 0) * 256;
    float* op = out + (((size_t)bi * NF + f) * C) * HW + p;   // frames 0..3 pass-through

    f32x4 acc[10];
#pragma unroll
    for (int m = 0; m < 10; m++) acc[m] = (f32x4){0.f, 0.f, 0.f, 0.f};

    for (int k = 0; k < 8; k++) {
        float xv[8];
#pragma unroll
        for (int j = 0; j < 8; j++) xv[j] = xp[(size_t)(k * 32 + cg * 8 + j) * HW];
        if (f < 4) {   // fused xm copy (block-uniform branch)
#pragma unroll
            for (int j = 0; j < 8; j++) op[(size_t)(k * 32 + cg * 8 + j) * HW] = xv[j];
        }
        short8v bfrag;
#pragma unroll
        for (int j = 0; j < 8; j++) bfrag[j] = (short)f2bf(xv[j]);
#pragma unroll
        for (int m = 0; m < 10; m++) {
            short8v afrag = *(const short8v*)(wrow + (size_t)(m * 16 + l15) * 256 + k * 32 + cg * 8);
            acc[m] = __builtin_amdgcn_mfma_f32_16x16x32_bf16(afrag, bfrag, acc[m], 0, 0, 0);
        }
    }

    float ssq = 0.f;
#pragma unroll
    for (int m = 0; m < 2; m++)
#pragma unroll
        for (int r = 0; r < 4; r++) ssq += acc[m][r] * acc[m][r];
    ssq += __shfl_xor(ssq, 16, 64);
    ssq += __shfl_xor(ssq, 32, 64);
    float rn = 1.0f / fmaxf(sqrtf(ssq), 1e-12f);

    if (f == 4) {
        float rq = rn * 1.44269504f;   // fold log2(e) into Q
        u16* kd = qkn + ((size_t)bi * NQ + p) * 32;
#pragma unroll
        for (int m = 0; m < 2; m++)
#pragma unroll
            for (int r = 0; r < 4; r++) kd[m * 16 + cg * 4 + r] = f2bf(acc[m][r] * rq);
        u16* ud = U + ((size_t)bi * HW + p) * 256;
#pragma unroll
        for (int m = 2; m < 10; m++) {
            int vo = m * 16 - 32 + cg * 4;
            union { u16 h[4]; uint2 v; } pk;
#pragma unroll
            for (int r = 0; r < 4; r++) pk.h[r] = f2bf(acc[m][r]);
            *(uint2*)(ud + vo) = pk.v;
        }
    } else {
        u16* kd = mkn + ((size_t)bi * NK + f * HW + p) * 32;
#pragma unroll
        for (int m = 0; m < 2; m++)
#pragma unroll
            for (int r = 0; r < 4; r++) kd[m * 16 + cg * 4 + r] = f2bf(acc[m][r] * rn);
#pragma unroll
        for (int m = 2; m < 10; m++)
#pragma unroll
            for (int r = 0; r < 4; r++) {
                int vo = m * 16 - 32 + cg * 4 + r;
                mvt[((size_t)bi * CV + vo) * NK + f * HW + p] = f2bf(acc[m][r]);
            }
    }
}

// ---------------- flash attention v17: merged-subtile wide pipeline ----------------
// Base = R22's 102.3-us config (K+V padded LDS, kc=8, pre-barrier prefetch, raw
// v_exp, setprio). R23 falsified the LDS-count model (K->regs: conflicts 0 but
// +0.9us); both pipes ~32% => serial-chain bound. Change: process BOTH 32-key
// subtiles per phase — 4 independent QK MFMAs, then 2x16 independent exps, both
// packs, then 16 PV MFMAs — giving every phase two independent chains for the
// scheduler to interleave (the old per-t setprio brackets forced separation).
// ~+24 live VGPR: 88 -> ~112 (+64 AGPR = 176, same 2-waves/SIMD bin).
__global__ __launch_bounds__(256, 2) void attn_k(
    const u16* __restrict__ qkn, const u16* __restrict__ mkn,
    const u16* __restrict__ mvt, u16* __restrict__ opart,
    float* __restrict__ lpart, int kc) {
    __shared__ alignas(16) u16 kl[2][64 * 40];    // [64 k][32 c + 8 pad] (80B rows)
    __shared__ alignas(16) u16 vl[2][128 * 72];   // [128 v][64 k + 8 pad] (144B rows)

    int bx = blockIdx.x;
    int bi = bx / (32 * kc);
    int rem = bx % (32 * kc);
    int qt = rem / kc, kci = rem % kc;
    int chunk = NK / kc, iters = chunk / 64;
    int tid = threadIdx.x, w = tid >> 6, lane = tid & 63;
    int l31 = lane & 31, hi = lane >> 5;

    int qrow = qt * 128 + w * 32 + l31;
    const u16* qp = qkn + ((size_t)bi * NQ + qrow) * 32;
    short8v qf0 = *(const short8v*)(qp + hi * 8);
    short8v qf1 = *(const short8v*)(qp + 16 + hi * 8);

    f32x16 O[4];
#pragma unroll
    for (int n = 0; n < 4; n++)
#pragma unroll
        for (int i = 0; i < 16; i++) O[n][i] = 0.f;
    float ls[4] = {0.f, 0.f, 0.f, 0.f};

    const u16* mknb = mkn + (size_t)bi * NK * 32;
    const u16* mvtb = mvt + (size_t)bi * CV * NK;
    int krow = tid >> 2, kcol = tid & 3;
    int klsoff = krow * 40 + kcol * 8;            // padded, no swizzle
    int vrow[4], vcol[4], vlsoff[4];
#pragma unroll
    for (int r = 0; r < 4; r++) {
        int cidx = tid + 256 * r;
        vrow[r] = cidx >> 3; vcol[r] = cidx & 7;
        vlsoff[r] = vrow[r] * 72 + vcol[r] * 8;   // padded, no swizzle
    }

    const u16* kptr = mknb + (size_t)(kci * chunk + krow) * 32 + kcol * 8;
    const u16* vptr[4];
#pragma unroll
    for (int r = 0; r < 4; r++)
        vptr[r] = mvtb + (size_t)vrow[r] * NK + kci * chunk + vcol[r] * 8;

    short8v kreg = *(const short8v*)kptr;
    short8v vreg[4];
#pragma unroll
    for (int r = 0; r < 4; r++) vreg[r] = *(const short8v*)vptr[r];

    int c = 0;
    for (int it = 0; it < iters; ++it) {
        *(short8v*)(&kl[c][0] + klsoff) = kreg;
#pragma unroll
        for (int r = 0; r < 4; r++) *(short8v*)(&vl[c][0] + vlsoff[r]) = vreg[r];
        if (it + 1 < iters) {   // prefetch next tile into regs (pre-barrier issue)
            kptr += 64 * 32;
            kreg = *(const short8v*)kptr;
#pragma unroll
            for (int r = 0; r < 4; r++) {
                vptr[r] += 64;
                vreg[r] = *(const short8v*)vptr[r];
            }
        }
        __syncthreads();
        const u16* klr = &kl[c][0];
        const u16* vlr = &vl[c][0];

        // ---- phase 1: QK^T for BOTH 32-key subtiles (4 independent MFMAs) ----
        const u16* kb0 = klr + (size_t)l31 * 40;
        const u16* kb1 = klr + (size_t)(32 + l31) * 40;
        short8v ka00 = *(const short8v*)(kb0 + hi * 8);
        short8v ka01 = *(const short8v*)(kb0 + (2 + hi) * 8);
        short8v ka10 = *(const short8v*)(kb1 + hi * 8);
        short8v ka11 = *(const short8v*)(kb1 + (2 + hi) * 8);
        f32x16 st0, st1;
#pragma unroll
        for (int i = 0; i < 16; i++) { st0[i] = 0.f; st1[i] = 0.f; }
        __builtin_amdgcn_s_setprio(1);
        st0 = __builtin_amdgcn_mfma_f32_32x32x16_bf16(ka00, qf0, st0, 0, 0, 0);
        st1 = __builtin_amdgcn_mfma_f32_32x32x16_bf16(ka10, qf0, st1, 0, 0, 0);
        st0 = __builtin_amdgcn_mfma_f32_32x32x16_bf16(ka01, qf1, st0, 0, 0, 0);
        st1 = __builtin_amdgcn_mfma_f32_32x32x16_bf16(ka11, qf1, st1, 0, 0, 0);
        __builtin_amdgcn_s_setprio(0);

        // ---- phase 2: softmax numerators for both subtiles (2 indep chains) ----
        float p0[16], p1[16];
#pragma unroll
        for (int i = 0; i < 16; i++) { p0[i] = exp2_raw(st0[i]); p1[i] = exp2_raw(st1[i]); }
#pragma unroll
        for (int g = 0; g < 4; g++)
            ls[g] += ((p0[4 * g] + p0[4 * g + 1]) + (p0[4 * g + 2] + p0[4 * g + 3]))
                   + ((p1[4 * g] + p1[4 * g + 1]) + (p1[4 * g + 2] + p1[4 * g + 3]));
        u32 ca0[4], ca1[4], cb0[4], cb1[4];
#pragma unroll
        for (int g = 0; g < 4; g++) {
            ca0[g] = cvtpk(p0[4 * g], p0[4 * g + 1]);
            ca1[g] = cvtpk(p0[4 * g + 2], p0[4 * g + 3]);
            cb0[g] = cvtpk(p1[4 * g], p1[4 * g + 1]);
            cb1[g] = cvtpk(p1[4 * g + 2], p1[4 * g + 3]);
        }

        // ---- phase 3: PV for all 4 k-slots (16 MFMAs; B-frags via permlane) ----
        __builtin_amdgcn_s_setprio(1);
#pragma unroll
        for (int kk = 0; kk < 4; kk++) {
            int sub = kk >> 1, half = kk & 1;
            u32* cc0 = sub ? cb0 : ca0;
            u32* cc1 = sub ? cb1 : ca1;
            i32x2 s0 = plswap(cc0[2 * half + 1], cc0[2 * half]);
            i32x2 s1 = plswap(cc1[2 * half + 1], cc1[2 * half]);
            union { u32 wd[4]; short8v v; } bu;
            bu.wd[0] = (u32)s0[1];
            bu.wd[1] = (u32)s1[1];
            bu.wd[2] = (u32)s0[0];
            bu.wd[3] = (u32)s1[0];
#pragma unroll
            for (int n = 0; n < 4; n++) {
                int vr = n * 32 + l31;
                short8v va = *(const short8v*)(vlr + vr * 72 + (kk * 2 + hi) * 8);
                O[n] = __builtin_amdgcn_mfma_f32_32x32x16_bf16(va, bu.v, O[n], 0, 0, 0);
            }
        }
        __builtin_amdgcn_s_setprio(0);
        c ^= 1;
    }

    float lsum = (ls[0] + ls[1]) + (ls[2] + ls[3]);
    lsum += __shfl_xor(lsum, 32, 64);
    uint2* op2 = (uint2*)opart;
    size_t pbase4 = (size_t)(bi * kc + kci) * 32;
#pragma unroll
    for (int n = 0; n < 4; n++)
#pragma unroll
        for (int g = 0; g < 4; g++) {
            uint2 val;
            val.x = cvtpk(O[n][4 * g + 0], O[n][4 * g + 1]);
            val.y = cvtpk(O[n][4 * g + 2], O[n][4 * g + 3]);
            int v4 = n * 8 + 2 * g + hi;   // v quad = (n*32 + 8g + 4hi)/4
            op2[(pbase4 + v4) * NQ + qrow] = val;
        }
    if (hi == 0) lpart[(size_t)(bi * kc + kci) * NQ + qrow] = lsum;
}

// ---------------- fused combine + output GEMM (+folded BN+ReLU) ----------------
// R17-measured form (32 px/block, grid 256). phase 1: sum kc bf16 partials,
// scale by 1/sum(l), stage agg in padded LDS; phase 2: 256x32 GEMM from
// U + agg-LDS, bias+relu. kc=8 halves phase-1 traffic (R22: -5.4 us total).
__global__ __launch_bounds__(256) void final_fused(
    const u16* __restrict__ opart, const float* __restrict__ lpart,
    const u16* __restrict__ U, const u16* __restrict__ wsf,
    const float* __restrict__ bias2, float* __restrict__ out, int kc) {
    __shared__ alignas(16) u16 aggL[32][136];   // [px][128 ch + 8 pad]
    __shared__ float lsumL[32];

    int bx = blockIdx.x;          // 2*128 = 256
    int bi = bx >> 7;
    int q0 = (bx & 127) * 32;
    int t = threadIdx.x;
    int px = t & 31, qs = t >> 5;   // qs 0..7

    if (qs == 0) {
        float s = 0.f;
        for (int k = 0; k < kc; k++) s += lpart[(size_t)(bi * kc + k) * NQ + q0 + px];
        lsumL[px] = 1.0f / s;
    }
    const uint2* op2 = (const uint2*)opart;
    float s[4][4];
#pragma unroll
    for (int j = 0; j < 4; j++)
#pragma unroll
        for (int e = 0; e < 4; e++) s[j][e] = 0.f;
    for (int k = 0; k < kc; k++) {
        size_t kb = (size_t)(bi * kc + k) * 32;
#pragma unroll
        for (int j = 0; j < 4; j++) {
            uint2 d = op2[(kb + qs * 4 + j) * NQ + q0 + px];
            s[j][0] += __uint_as_float(d.x << 16);
            s[j][1] += __uint_as_float(d.x & 0xFFFF0000u);
            s[j][2] += __uint_as_float(d.y << 16);
            s[j][3] += __uint_as_float(d.y & 0xFFFF0000u);
        }
    }
    __syncthreads();   // lsumL ready
    float r = lsumL[px];
#pragma unroll
    for (int j = 0; j < 4; j++) {
        uint2 v;
        v.x = cvtpk(s[j][0] * r, s[j][1] * r);
        v.y = cvtpk(s[j][2] * r, s[j][3] * r);
        *(uint2*)(&aggL[px][(qs * 4 + j) * 4]) = v;
    }
    __syncthreads();   // aggL ready

    int w = t >> 6, lane = t & 63;
    int l15 = lane & 15, cg = lane >> 4;
    f32x4 acc[4][2];
#pragma unroll
    for (int m = 0; m < 4; m++)
#pragma unroll
        for (int n = 0; n < 2; n++) acc[m][n] = (f32x4){0.f, 0.f, 0.f, 0.f};
    const u16* ub = U + ((size_t)bi * HW + q0) * 256;
    for (int k8 = 0; k8 < 8; k8++) {
        short8v bfrag[2];
#pragma unroll
        for (int n = 0; n < 2; n++) {
            int pxr = n * 16 + l15;
            if (k8 < 4) bfrag[n] = *(const short8v*)(ub + (size_t)pxr * 256 + k8 * 32 + cg * 8);
            else        bfrag[n] = *(const short8v*)(&aggL[pxr][(k8 - 4) * 32 + cg * 8]);
        }
#pragma unroll
        for (int m = 0; m < 4; m++) {
            short8v afrag = *(const short8v*)(wsf + (size_t)(w * 64 + m * 16 + l15) * 256 + k8 * 32 + cg * 8);
#pragma unroll
            for (int n = 0; n < 2; n++)
                acc[m][n] = __builtin_amdgcn_mfma_f32_16x16x32_bf16(afrag, bfrag[n], acc[m][n], 0, 0, 0);
        }
    }
    float* obase = out + (((size_t)bi * NF + 4) * C) * HW;
#pragma unroll
    for (int m = 0; m < 4; m++)
#pragma unroll
        for (int n = 0; n < 2; n++)
#pragma unroll
            for (int rr = 0; rr < 4; rr++) {
                int o = w * 64 + m * 16 + cg * 4 + rr;
                int px2 = n * 16 + l15;
                obase[(size_t)o * HW + q0 + px2] = fmaxf(acc[m][n][rr] + bias2[o], 0.f);
            }
}

extern "C" void kernel_launch(void* const* d_in, const int* in_sizes, int n_in,
                              void* d_out, int out_size, void* d_ws, size_t ws_size,
                              hipStream_t stream) {
    const float* x    = (const float*)d_in[0];
    const float* qk_w = (const float*)d_in[2];
    const float* qv_w = (const float*)d_in[3];
    const float* mk_w = (const float*)d_in[4];
    const float* mv_w = (const float*)d_in[5];
    const float* sm_w = (const float*)d_in[6];
    const float* bns  = (const float*)d_in[7];
    const float* bnb  = (const float*)d_in[8];
    const float* bnm  = (const float*)d_in[9];
    const float* bnv  = (const float*)d_in[10];
    float* out = (float*)d_out;
    char* ws = (char*)d_ws;

    size_t off = 0;
    auto alloc = [&](size_t bytes) { size_t o = off; off += (bytes + 255) & ~(size_t)255; return o; };
    size_t WSF = alloc(256 * 256 * 2);
    size_t BIA = alloc(256 * 4);
    size_t WB  = alloc(2 * 160 * 256 * 2);
    size_t QKN = alloc((size_t)B * NQ * 32 * 2);
    size_t MKN = alloc((size_t)B * NK * 32 * 2);
    size_t MVT = alloc((size_t)B * CV * NK * 2);
    size_t UBU = alloc((size_t)B * HW * 256 * 2);
    int kc = 8;   // R22-measured best: halves opart/lpart traffic
    size_t LP = alloc((size_t)B * kc * NQ * 4);
    size_t OP = alloc((size_t)B * kc * (size_t)CV * NQ * 2);

    prep_k<<<577, 256, 0, stream>>>(qk_w, qv_w, mk_w, mv_w, sm_w, bns, bnb, bnm, bnv,
        (u16*)(ws + WSF), (float*)(ws + BIA), (u16*)(ws + WB));
    proj_mfma<<<640, 256, 0, stream>>>(x, (u16*)(ws + WB),
        (u16*)(ws + QKN), (u16*)(ws + MKN), (u16*)(ws + MVT), (u16*)(ws + UBU), out);
    attn_k<<<B * 32 * kc, 256, 0, stream>>>((u16*)(ws + QKN), (u16*)(ws + MKN),
        (u16*)(ws + MVT), (u16*)(ws + OP), (float*)(ws + LP), kc);
    final_fused<<<256, 256, 0, stream>>>((u16*)(ws + OP), (float*)(ws + LP),
        (u16*)(ws + UBU), (u16*)(ws + WSF), (float*)(ws + BIA), out, kc);
}